// Round 1
// baseline (85.308 us; speedup 1.0000x reference)
//
#include <hip/hip_runtime.h>
#include <hip/hip_bf16.h>

#define N_ 4096
#define D_ 768
#define NCLS 128
#define BM 128
#define BN 128
#define BK 32
#define LDK 40  // padded LDS row stride (bf16 elems): 80B, 16B-aligned, spreads banks

typedef __bf16 bf16x8 __attribute__((ext_vector_type(8)));
typedef float f32x4 __attribute__((ext_vector_type(4)));
typedef short s16x8 __attribute__((ext_vector_type(8)));

__global__ __launch_bounds__(256) void hist_kernel(const int* __restrict__ labels,
                                                   int* __restrict__ hist) {
  int i = blockIdx.x * 256 + threadIdx.x;
  if (i < N_) atomicAdd(&hist[labels[i]], 1);
}

__global__ __launch_bounds__(256) void normalize_kernel(const float* __restrict__ src,
                                                        __hip_bfloat16* __restrict__ dst) {
  int row = blockIdx.x;
  const float* s = src + (size_t)row * D_;
  float v0 = s[threadIdx.x];
  float v1 = s[threadIdx.x + 256];
  float v2 = s[threadIdx.x + 512];
  float ss = v0 * v0 + v1 * v1 + v2 * v2;
#pragma unroll
  for (int m = 32; m; m >>= 1) ss += __shfl_xor(ss, m);
  __shared__ float wsum[4];
  int lane = threadIdx.x & 63, w = threadIdx.x >> 6;
  if (lane == 0) wsum[w] = ss;
  __syncthreads();
  float tot = wsum[0] + wsum[1] + wsum[2] + wsum[3];
  float inv = 1.0f / fmaxf(sqrtf(tot), 1e-8f);
  __hip_bfloat16* d = dst + (size_t)row * D_;
  d[threadIdx.x] = __float2bfloat16(v0 * inv);
  d[threadIdx.x + 256] = __float2bfloat16(v1 * inv);
  d[threadIdx.x + 512] = __float2bfloat16(v2 * inv);
}

__global__ __launch_bounds__(256) void gemm_epi_kernel(
    const unsigned short* __restrict__ A, const unsigned short* __restrict__ B,
    const int* __restrict__ labels, float* __restrict__ row_part,
    float* __restrict__ col_part, float* __restrict__ S_part) {
  __shared__ __align__(16) unsigned short As[BM * LDK];
  __shared__ __align__(16) unsigned short Bs[BN * LDK];
  __shared__ int labR[BM], labC[BN];
  __shared__ float rbuf[2][BM], cbuf[2][BN];
  __shared__ float sbuf[4];

  const int bx = blockIdx.x, by = blockIdx.y;
  const int tid = threadIdx.x;
  const int lane = tid & 63, wave = tid >> 6;
  const int wr = wave >> 1, wc = wave & 1;
  const int g = lane >> 4, fr = lane & 15;
  const int rowBase = by * BM, colBase = bx * BN;

  if (tid < BM) labR[tid] = labels[rowBase + tid];
  else labC[tid - BM] = labels[colBase + tid - BM];

  f32x4 acc[4][4] = {};

  for (int k0 = 0; k0 < D_; k0 += BK) {
    __syncthreads();
#pragma unroll
    for (int c = tid; c < 512; c += 256) {
      int r = c >> 2, k8 = (c & 3) * 8;
      s16x8 va = *(const s16x8*)(A + (size_t)(rowBase + r) * D_ + k0 + k8);
      s16x8 vb = *(const s16x8*)(B + (size_t)(colBase + r) * D_ + k0 + k8);
      *(s16x8*)(As + r * LDK + k8) = va;
      *(s16x8*)(Bs + r * LDK + k8) = vb;
    }
    __syncthreads();
    bf16x8 af[4], bfr[4];
#pragma unroll
    for (int m = 0; m < 4; ++m)
      af[m] = *(const bf16x8*)(As + (wr * 64 + m * 16 + fr) * LDK + g * 8);
#pragma unroll
    for (int n = 0; n < 4; ++n)
      bfr[n] = *(const bf16x8*)(Bs + (wc * 64 + n * 16 + fr) * LDK + g * 8);
#pragma unroll
    for (int m = 0; m < 4; ++m)
#pragma unroll
      for (int n = 0; n < 4; ++n)
        acc[m][n] = __builtin_amdgcn_mfma_f32_16x16x32_bf16(af[m], bfr[n], acc[m][n], 0, 0, 0);
  }
  __syncthreads();

  const float scale = 14.285714285714286f;  // 1/0.07
  float sPart = 0.f;
  float colAcc[4] = {0.f, 0.f, 0.f, 0.f};
#pragma unroll
  for (int m = 0; m < 4; ++m) {
    float ra[4] = {0.f, 0.f, 0.f, 0.f};
#pragma unroll
    for (int n = 0; n < 4; ++n) {
      int col = wc * 64 + n * 16 + fr;
      int lc = labC[col];
#pragma unroll
      for (int r = 0; r < 4; ++r) {
        float v = acc[m][n][r] * scale;
        float e = __expf(v);
        ra[r] += e;
        colAcc[n] += e;
        int row = wr * 64 + m * 16 + g * 4 + r;
        if (labR[row] == lc) sPart += v;
      }
    }
#pragma unroll
    for (int r = 0; r < 4; ++r) {
      float x = ra[r];
      x += __shfl_xor(x, 1);
      x += __shfl_xor(x, 2);
      x += __shfl_xor(x, 4);
      x += __shfl_xor(x, 8);
      if (fr == 0) rbuf[wc][wr * 64 + m * 16 + g * 4 + r] = x;
    }
  }
#pragma unroll
  for (int n = 0; n < 4; ++n) {
    float x = colAcc[n];
    x += __shfl_xor(x, 16);
    x += __shfl_xor(x, 32);
    if (g == 0) cbuf[wr][wc * 64 + n * 16 + fr] = x;
  }
  float s = sPart;
#pragma unroll
  for (int m = 32; m; m >>= 1) s += __shfl_xor(s, m);
  if (lane == 0) sbuf[wave] = s;
  __syncthreads();
  if (tid < BM)
    row_part[(size_t)bx * N_ + rowBase + tid] = rbuf[0][tid] + rbuf[1][tid];
  else
    col_part[(size_t)by * N_ + colBase + (tid - BM)] = cbuf[0][tid - BM] + cbuf[1][tid - BM];
  if (tid == 0) S_part[by * 32 + bx] = sbuf[0] + sbuf[1] + sbuf[2] + sbuf[3];
}

__global__ __launch_bounds__(256) void reduce_kernel(
    const float* __restrict__ row_part, const float* __restrict__ col_part,
    const float* __restrict__ S_part, const int* __restrict__ labels,
    const int* __restrict__ hist, double* __restrict__ accs) {
  int i = blockIdx.x * 256 + threadIdx.x;  // 0..4095
  float rs = 0.f, cs = 0.f;
#pragma unroll
  for (int b = 0; b < 32; ++b) {
    rs += row_part[(size_t)b * N_ + i];
    cs += col_part[(size_t)b * N_ + i];
  }
  int cnt = hist[labels[i]];
  double term = (double)cnt * ((double)logf(rs) + (double)logf(cs));
  double sterm = (i < 1024) ? (double)S_part[i] : 0.0;
#pragma unroll
  for (int m = 32; m; m >>= 1) {
    term += __shfl_xor(term, m);
    sterm += __shfl_xor(sterm, m);
  }
  __shared__ double tbuf[4], sb[4];
  int lane = threadIdx.x & 63, w = threadIdx.x >> 6;
  if (lane == 0) { tbuf[w] = term; sb[w] = sterm; }
  __syncthreads();
  if (threadIdx.x == 0) {
    atomicAdd(&accs[0], tbuf[0] + tbuf[1] + tbuf[2] + tbuf[3]);
    atomicAdd(&accs[1], sb[0] + sb[1] + sb[2] + sb[3]);
  }
}

__global__ void final_kernel(const double* __restrict__ accs, float* __restrict__ out) {
  out[0] = (float)((accs[0] - 2.0 * accs[1]) / (2.0 * (double)N_));
}

extern "C" void kernel_launch(void* const* d_in, const int* in_sizes, int n_in,
                              void* d_out, int out_size, void* d_ws, size_t ws_size,
                              hipStream_t stream) {
  const float* img = (const float*)d_in[0];
  const float* txt = (const float*)d_in[1];
  const int* labels = (const int*)d_in[2];
  float* out = (float*)d_out;
  char* ws = (char*)d_ws;

  // workspace layout (bytes)
  __hip_bfloat16* img_nb = (__hip_bfloat16*)(ws);                 //  6,291,456
  __hip_bfloat16* txt_nb = (__hip_bfloat16*)(ws + 6291456);       //  6,291,456
  float* row_part = (float*)(ws + 12582912);                      //    524,288 (32 x 4096)
  float* col_part = (float*)(ws + 13107200);                      //    524,288
  float* S_part = (float*)(ws + 13631488);                        //      4,096
  int* hist = (int*)(ws + 13635584);                              //        512
  double* accs = (double*)(ws + 13636096);                        //         16

  hipMemsetAsync(ws + 13635584, 0, 512 + 16, stream);  // hist + accs
  hist_kernel<<<16, 256, 0, stream>>>(labels, hist);
  normalize_kernel<<<N_, 256, 0, stream>>>(img, img_nb);
  normalize_kernel<<<N_, 256, 0, stream>>>(txt, txt_nb);
  gemm_epi_kernel<<<dim3(32, 32), 256, 0, stream>>>(
      (const unsigned short*)img_nb, (const unsigned short*)txt_nb, labels,
      row_part, col_part, S_part);
  reduce_kernel<<<16, 256, 0, stream>>>(row_part, col_part, S_part, labels, hist, accs);
  final_kernel<<<1, 1, 0, stream>>>(accs, out);
}

// Round 2
// 83.538 us; speedup vs baseline: 1.0212x; 1.0212x over previous
//
#include <hip/hip_runtime.h>
#include <hip/hip_bf16.h>

#define N_ 4096
#define D_ 768
#define NCLS 128
#define BM 128
#define BN 128
#define BK 32

typedef __bf16 bf16x8 __attribute__((ext_vector_type(8)));
typedef float f32x4 __attribute__((ext_vector_type(4)));

__device__ __forceinline__ void gload16(const unsigned short* g, unsigned short* l) {
  __builtin_amdgcn_global_load_lds(
      (const __attribute__((address_space(1))) unsigned int*)g,
      (__attribute__((address_space(3))) unsigned int*)l, 16, 0, 0);
}

// Normalize both embedding matrices in one launch (blocks [0,N) -> img, [N,2N) -> txt)
__global__ __launch_bounds__(256) void normalize_kernel(
    const float* __restrict__ img, const float* __restrict__ txt,
    __hip_bfloat16* __restrict__ img_nb, __hip_bfloat16* __restrict__ txt_nb) {
  int b = blockIdx.x;
  const float* s;
  __hip_bfloat16* d;
  if (b < N_) {
    s = img + (size_t)b * D_;
    d = img_nb + (size_t)b * D_;
  } else {
    s = txt + (size_t)(b - N_) * D_;
    d = txt_nb + (size_t)(b - N_) * D_;
  }
  float v0 = s[threadIdx.x];
  float v1 = s[threadIdx.x + 256];
  float v2 = s[threadIdx.x + 512];
  float ss = v0 * v0 + v1 * v1 + v2 * v2;
#pragma unroll
  for (int m = 32; m; m >>= 1) ss += __shfl_xor(ss, m);
  __shared__ float wsum[4];
  int lane = threadIdx.x & 63, w = threadIdx.x >> 6;
  if (lane == 0) wsum[w] = ss;
  __syncthreads();
  float tot = wsum[0] + wsum[1] + wsum[2] + wsum[3];
  float inv = 1.0f / fmaxf(sqrtf(tot), 1e-8f);
  d[threadIdx.x] = __float2bfloat16(v0 * inv);
  d[threadIdx.x + 256] = __float2bfloat16(v1 * inv);
  d[threadIdx.x + 512] = __float2bfloat16(v2 * inv);
}

// GEMM with fused exp-sum epilogue. LDS layout per tile: [g=k/8][row][8 bf16]
// (chunk-linear, filled by global_load_lds with pre-swizzled global addresses;
// fragment ds_read_b128 is conflict-free: 16 consecutive chunks per quarter-wave)
__global__ __launch_bounds__(256) void gemm_epi_kernel(
    const unsigned short* __restrict__ A, const unsigned short* __restrict__ B,
    const int* __restrict__ labels, float* __restrict__ row_part,
    float* __restrict__ col_part, float* __restrict__ S_part) {
  __shared__ __align__(16) unsigned short As[4096];  // 4 chunks x 128 rows x 8 elems
  __shared__ __align__(16) unsigned short Bs[4096];
  __shared__ int labR[BM], labC[BN];
  __shared__ float rbuf[2][BM], cbuf[2][BN];
  __shared__ float sbuf[4];

  const int bx = blockIdx.x, by = blockIdx.y;
  const int tid = threadIdx.x;
  const int lane = tid & 63, wave = tid >> 6;
  const int wr = wave >> 1, wc = wave & 1;
  const int g = lane >> 4, fr = lane & 15;
  const int rowBase = by * BM, colBase = bx * BN;

  if (tid < BM) labR[tid] = labels[rowBase + tid];
  else labC[tid - BM] = labels[colBase + tid - BM];

  // staging coordinates for this thread (fixed across K-steps)
  int c0_0 = wave * 64;            // chunks [0,256): i=0
  int c0_1 = 256 + wave * 64;      // chunks [256,512): i=1
  int cA0 = c0_0 + lane, cA1 = c0_1 + lane;
  int r0 = cA0 & 127, g0 = cA0 >> 7;
  int r1 = cA1 & 127, g1 = cA1 >> 7;
  const unsigned short* srcA0 = A + (size_t)(rowBase + r0) * D_ + g0 * 8;
  const unsigned short* srcA1 = A + (size_t)(rowBase + r1) * D_ + g1 * 8;
  const unsigned short* srcB0 = B + (size_t)(colBase + r0) * D_ + g0 * 8;
  const unsigned short* srcB1 = B + (size_t)(colBase + r1) * D_ + g1 * 8;

  f32x4 acc[4][4] = {};

  for (int k0 = 0; k0 < D_; k0 += BK) {
    __syncthreads();  // previous iteration's ds_reads complete
    gload16(srcA0 + k0, &As[c0_0 * 8]);
    gload16(srcB0 + k0, &Bs[c0_0 * 8]);
    gload16(srcA1 + k0, &As[c0_1 * 8]);
    gload16(srcB1 + k0, &Bs[c0_1 * 8]);
    __syncthreads();  // vmcnt(0) drain: tile resident

    bf16x8 af[4], bfr[4];
#pragma unroll
    for (int m = 0; m < 4; ++m)
      af[m] = *(const bf16x8*)&As[g * 1024 + (wr * 64 + m * 16 + fr) * 8];
#pragma unroll
    for (int n = 0; n < 4; ++n)
      bfr[n] = *(const bf16x8*)&Bs[g * 1024 + (wc * 64 + n * 16 + fr) * 8];
#pragma unroll
    for (int m = 0; m < 4; ++m)
#pragma unroll
      for (int n = 0; n < 4; ++n)
        acc[m][n] = __builtin_amdgcn_mfma_f32_16x16x32_bf16(af[m], bfr[n], acc[m][n], 0, 0, 0);
  }
  __syncthreads();

  const float scale = 14.285714285714286f;  // 1/0.07
  float sPart = 0.f;
  float colAcc[4] = {0.f, 0.f, 0.f, 0.f};
#pragma unroll
  for (int m = 0; m < 4; ++m) {
    float ra[4] = {0.f, 0.f, 0.f, 0.f};
#pragma unroll
    for (int n = 0; n < 4; ++n) {
      int col = wc * 64 + n * 16 + fr;
      int lc = labC[col];
#pragma unroll
      for (int r = 0; r < 4; ++r) {
        float v = acc[m][n][r] * scale;
        float e = __expf(v);
        ra[r] += e;
        colAcc[n] += e;
        int row = wr * 64 + m * 16 + g * 4 + r;
        if (labR[row] == lc) sPart += v;
      }
    }
#pragma unroll
    for (int r = 0; r < 4; ++r) {
      float x = ra[r];
      x += __shfl_xor(x, 1);
      x += __shfl_xor(x, 2);
      x += __shfl_xor(x, 4);
      x += __shfl_xor(x, 8);
      if (fr == 0) rbuf[wc][wr * 64 + m * 16 + g * 4 + r] = x;
    }
  }
#pragma unroll
  for (int n = 0; n < 4; ++n) {
    float x = colAcc[n];
    x += __shfl_xor(x, 16);
    x += __shfl_xor(x, 32);
    if (g == 0) cbuf[wr][wc * 64 + n * 16 + fr] = x;
  }
  float s = sPart;
#pragma unroll
  for (int m = 32; m; m >>= 1) s += __shfl_xor(s, m);
  if (lane == 0) sbuf[wave] = s;
  __syncthreads();
  if (tid < BM)
    row_part[(size_t)bx * N_ + rowBase + tid] = rbuf[0][tid] + rbuf[1][tid];
  else
    col_part[(size_t)by * N_ + colBase + (tid - BM)] = cbuf[0][tid - BM] + cbuf[1][tid - BM];
  if (tid == 0) S_part[by * 32 + bx] = sbuf[0] + sbuf[1] + sbuf[2] + sbuf[3];
}

// Per-block local histogram (no separate hist kernel, no memset), partials out (no atomics)
__global__ __launch_bounds__(256) void reduce_kernel(
    const float* __restrict__ row_part, const float* __restrict__ col_part,
    const float* __restrict__ S_part, const int* __restrict__ labels,
    double* __restrict__ partials) {
  __shared__ int hist[NCLS];
  int tid = threadIdx.x;
  if (tid < NCLS) hist[tid] = 0;
  __syncthreads();
  for (int j = tid; j < N_; j += 256) atomicAdd(&hist[labels[j]], 1);
  __syncthreads();

  int i = blockIdx.x * 256 + tid;  // 0..4095
  float rs = 0.f, cs = 0.f;
#pragma unroll
  for (int b = 0; b < 32; ++b) {
    rs += row_part[(size_t)b * N_ + i];
    cs += col_part[(size_t)b * N_ + i];
  }
  int cnt = hist[labels[i]];
  double term = (double)cnt * ((double)logf(rs) + (double)logf(cs));
  double sterm = (i < 1024) ? (double)S_part[i] : 0.0;
#pragma unroll
  for (int m = 32; m; m >>= 1) {
    term += __shfl_xor(term, m);
    sterm += __shfl_xor(sterm, m);
  }
  __shared__ double tbuf[4], sb[4];
  int lane = tid & 63, w = tid >> 6;
  if (lane == 0) { tbuf[w] = term; sb[w] = sterm; }
  __syncthreads();
  if (tid == 0) {
    partials[blockIdx.x] = tbuf[0] + tbuf[1] + tbuf[2] + tbuf[3];
    partials[16 + blockIdx.x] = sb[0] + sb[1] + sb[2] + sb[3];
  }
}

__global__ void final_kernel(const double* __restrict__ partials, float* __restrict__ out) {
  double t = 0.0, s = 0.0;
#pragma unroll
  for (int i = 0; i < 16; ++i) {
    t += partials[i];
    s += partials[16 + i];
  }
  out[0] = (float)((t - 2.0 * s) / (2.0 * (double)N_));
}

extern "C" void kernel_launch(void* const* d_in, const int* in_sizes, int n_in,
                              void* d_out, int out_size, void* d_ws, size_t ws_size,
                              hipStream_t stream) {
  const float* img = (const float*)d_in[0];
  const float* txt = (const float*)d_in[1];
  const int* labels = (const int*)d_in[2];
  float* out = (float*)d_out;
  char* ws = (char*)d_ws;

  // workspace layout (bytes)
  __hip_bfloat16* img_nb = (__hip_bfloat16*)(ws);             //  6,291,456
  __hip_bfloat16* txt_nb = (__hip_bfloat16*)(ws + 6291456);   //  6,291,456
  float* row_part = (float*)(ws + 12582912);                  //    524,288 (32 x 4096)
  float* col_part = (float*)(ws + 13107200);                  //    524,288
  float* S_part = (float*)(ws + 13631488);                    //      4,096
  double* partials = (double*)(ws + 13635584);                //        256

  normalize_kernel<<<2 * N_, 256, 0, stream>>>(img, txt, img_nb, txt_nb);
  gemm_epi_kernel<<<dim3(32, 32), 256, 0, stream>>>(
      (const unsigned short*)img_nb, (const unsigned short*)txt_nb, labels,
      row_part, col_part, S_part);
  reduce_kernel<<<16, 256, 0, stream>>>(row_part, col_part, S_part, labels, partials);
  final_kernel<<<1, 1, 0, stream>>>(partials, out);
}